// Round 12
// baseline (70.889 us; speedup 1.0000x reference)
//
#include <hip/hip_runtime.h>

// Problem constants (fixed by setup_inputs in the reference)
constexpr int N_  = 8;
constexpr int B_  = 64;
constexpr int C_  = 32;
constexpr int H_  = 256;
constexpr int W_  = 256;
constexpr int PH_ = 8;
constexpr int HW_ = H_ * W_;
constexpr int NB_ = N_ * B_;
constexpr int CAP_ = 4992;    // floats of LDS (19.5 KB) -> 8 blocks/CU
                              // worst half-window <= 135x35 = 4725 (see proof in notes)

// One block = (box, channel, j-half), XCD-clustered (all 64 blocks of a box on
// one XCD). Stage the half's ROI window into LDS with coalesced
// global_load_lds, ONE barrier, then sample from LDS. No scattered global
// gathers (r5-r11: pinned ~62us at any MLP/instr count -> TA line-throughput
// bound: tall-box gathers touch ~64 lines/instr). Overlap comes from 8
// resident blocks/CU (TLP), not intra-block pipelining (r10's barrier-drain).
__global__ __launch_bounds__(256)
void boxpool_v12(const float* __restrict__ x, const float* __restrict__ boxes,
                 float* __restrict__ out, int MW, int PM, int jper, unsigned Mj,
                 long featsSize)
{
    __shared__ float roi[CAP_];

    const int Bx   = blockIdx.x;
    const int xcd  = Bx & 7;           // round-robin dispatch -> XCD (perf-only)
    const int s    = Bx >> 3;          // 0 .. NB_/8 * 64 - 1
    const int nb   = xcd * (NB_ / 8) + (s >> 6);
    const int rem  = s & 63;
    const int c    = rem >> 1;
    const int half = rem & 1;
    const int tid  = threadIdx.x;
    const int n    = nb >> 6;          // B_ = 64

    // ---- box parameters (uniform -> scalar)
    const float* bp = boxes + (long)nb * 4;
    const float xmin = bp[0], ymin = bp[1], xmax = bp[2], ymax = bp[3];
    const bool is_zero = (xmin == 0.f) && (ymin == 0.f) && (xmax == 0.f) && (ymax == 0.f);
    const float bw = xmax - xmin, bh = ymax - ymin;
    const bool wide = bw > bh;
    float den = wide ? bh : bw;
    den = (den == 0.f) ? 1.f : den;
    const float ratio = (wide ? bw : bh) / den;
    const float wf = ceilf(ratio * (float)PH_);
    const float wm1 = (wf > 1.f) ? (wf - 1.f) : 1.f;
    const int   wfi = is_zero ? 0 : (int)wf;

    if (c == 0 && half == 0 && tid == 0) {
        float wv = is_zero ? 0.f : wf;
        out[featsSize + (long)nb * 2 + 0] = wv;
        out[featsSize + (long)nb * 2 + 1] = wv;
    }

    const int jlo  = half * jper;
    const int nv   = min(jper, wfi - jlo);   // # valid j in this half (<=0 => none)
    const int npts = PH_ * jper;

    float* ob  = out + (long)nb * (2 * C_ * PM) + (long)c * PM;  // d=0 channel base
    float* ob1 = ob + (long)C_ * PM;                             // d=1 channel base

    if (nv <= 0) {
        // whole half invalid (or zero box): zeros at direct positions, both dirs
        for (int p = tid; p < npts; p += 256) {
            const int i  = (int)(((unsigned)p * Mj) >> 16);
            const int jj = p - i * jper;
            const int j  = jlo + jj;
            if (j >= MW) continue;
            ob [(long)i * MW + j] = 0.f;
            ob1[(long)i * MW + j] = 0.f;
        }
        return;
    }

    // ---- geometry shared by staging and sampling
    const float inv7 = 1.f / 7.f;
    const float ew = bw / wm1;      // wide: x step per j
    const float et = bh / wm1;      // tall: y step per j

    float xs_lo, xs_hi, ys_lo, ys_hi;
    if (wide) {
        xs_lo = xmin + (float)jlo * ew;
        xs_hi = xmin + (float)(jlo + nv - 1) * ew;
        ys_lo = ymin;
        ys_hi = ymin + bh;
    } else {
        ys_hi = ymin + (wf - (float)jlo) * et;            // j ascending -> ys descending
        ys_lo = ymin + (wf - (float)(jlo + nv - 1)) * et;
        xs_lo = xmin;
        xs_hi = xmin + bw;
    }
    const int gx0 = min(max((int)floorf(xs_lo - 0.5f), 0), W_ - 1);
    const int gx1 = min(max((int)floorf(xs_hi - 0.5f) + 1, 0), W_ - 1);
    const int gy0 = min(max((int)floorf(ys_lo - 0.5f), 0), H_ - 1);
    const int gy1 = min(max((int)floorf(ys_hi - 0.5f) + 1, 0), H_ - 1);
    const int rw  = gx1 - gx0 + 1;
    const int rwp = rw | 1;                      // odd stride -> bank spread
    int rh = gy1 - gy0 + 1;
    if (rh * rwp > CAP_) rh = CAP_ / rwp;        // defensive (unreachable w/ data)

    // ---- stage window -> LDS (coalesced rows; 4B direct-to-LDS)
    const int wid = tid >> 6, lane = tid & 63;
    const float* plane = x + (long)(n * C_ + c) * HW_;
    for (int r = wid; r < rh; r += 4) {
        const float* grow = plane + (gy0 + r) * W_ + gx0;
        float* lrow = &roi[r * rwp];
        for (int cc = 0; cc < rw; cc += 64) {
            if (cc + lane < rw) {
                __builtin_amdgcn_global_load_lds(
                    (const __attribute__((address_space(1))) unsigned int*)(grow + cc + lane),
                    (__attribute__((address_space(3))) unsigned int*)(lrow + cc),
                    4, 0, 0);
            }
        }
    }
    __syncthreads();   // one drain per block; overlap across 8 resident blocks

    // ---- sample from LDS; write both directions
    for (int p = tid; p < npts; p += 256) {
        const int i  = (int)(((unsigned)p * Mj) >> 16);
        const int jj = p - i * jper;
        const int j  = jlo + jj;
        if (j >= MW) continue;

        float v = 0.f;
        long o1idx;
        if (jj < nv) {
            const float fi = (float)i, fj = (float)j;
            float xs, ys;
            if (wide) { xs = xmin + fj * ew;          ys = ymin + fi * (bh * inv7); }
            else      { xs = xmin + fi * (bw * inv7); ys = ymin + (wf - fj) * et;   }
            const float ix = xs - 0.5f, iy = ys - 0.5f;
            const float x0f = floorf(ix), y0f = floorf(iy);
            const int x0 = (int)x0f, y0 = (int)y0f;

            float wx1 = ix - x0f, wx0 = 1.f - wx1;
            float wy1 = iy - y0f, wy0 = 1.f - wy1;
            if (y0 < 0 || y0 >= H_)         wy0 = 0.f;
            if (y0 + 1 < 0 || y0 + 1 >= H_) wy1 = 0.f;
            const int y0c = min(max(y0, 0), H_ - 1);
            const int y1c = min(max(y0 + 1, 0), H_ - 1);
            if (x0 < 0 || x0 >= W_)         wx0 = 0.f;
            if (x0 + 1 < 0 || x0 + 1 >= W_) wx1 = 0.f;
            const int bx = min(max(x0, 0), W_ - 2);
            const float wl = (bx == x0) ? wx0 : ((bx == x0 + 1) ? wx1 : 0.f);
            const float wr = (bx + 1 == x0 + 1) ? wx1 : ((bx + 1 == x0) ? wx0 : 0.f);

            const int xl  = min(max(bx - gx0, 0), max(rw - 2, 0));
            const int y0l = min(max(y0c - gy0, 0), rh - 1);
            const int y1l = min(max(y1c - gy0, 0), rh - 1);

            v = (wl * wy0) * roi[y0l * rwp + xl] + (wr * wy0) * roi[y0l * rwp + xl + 1]
              + (wl * wy1) * roi[y1l * rwp + xl] + (wr * wy1) * roi[y1l * rwp + xl + 1];

            const int i2 = (PH_ - 1) - i;
            const int j2 = wfi - 1 - j;
            o1idx = (long)i2 * MW + j2;     // valid -> flipped position
        } else {
            o1idx = (long)i * MW + j;       // invalid -> zero at direct position
        }
        ob [(long)i * MW + j] = v;
        ob1[o1idx] = v;
    }
}

extern "C" void kernel_launch(void* const* d_in, const int* in_sizes, int n_in,
                              void* d_out, int out_size, void* d_ws, size_t ws_size,
                              hipStream_t stream)
{
    const float* x     = (const float*)d_in[0];
    const float* boxes = (const float*)d_in[1];
    float* out = (float*)d_out;

    long total      = (long)out_size;
    long widthsSize = (long)N_ * B_ * 2;
    long featsSize  = total - widthsSize;
    int  MW         = (int)(featsSize / ((long)N_ * B_ * 2 * C_ * PH_));
    int  PM         = PH_ * MW;

    int jper = (MW + 1) / 2;                                      // j's per half
    unsigned Mj = (65536u + (unsigned)jper - 1u) / (unsigned)jper; // p/jper magic

    // grid: 8 XCD clusters x 64 boxes x 32 channels x 2 halves
    int blocks = NB_ * C_ * 2;
    hipLaunchKernelGGL(boxpool_v12, dim3(blocks), dim3(256), 0, stream,
                       x, boxes, out, MW, PM, jper, Mj, featsSize);
}

// Round 13
// 55.144 us; speedup vs baseline: 1.2855x; 1.2855x over previous
//
#include <hip/hip_runtime.h>

// Problem constants (fixed by setup_inputs in the reference)
constexpr int N_  = 8;
constexpr int B_  = 64;
constexpr int C_  = 32;
constexpr int H_  = 256;
constexpr int W_  = 256;
constexpr int PH_ = 8;
constexpr int HW_ = H_ * W_;
constexpr int NB_ = N_ * B_;
constexpr int CAP_ = 6656;    // floats of LDS (26 KB) -> 6 blocks/CU
                              // worst half-window: rh <= 4*jper+3, stride <= 44 (tall)
                              // or rh <= 34, stride <= ~140 (wide); both < 6656 for MW<=65

// One block = (box, channel, j-half), XCD-clustered. Stage the half's ROI into
// LDS, one barrier, sample from LDS (r12 removed scattered gathers; VALUBusy
// hit 69% -> VALU-bound on 4B-granular staging address math). r13: staging in
// 16B chunks (global_load_lds dwordx4) with flat chunk indexing -> ~6x fewer
// staging instructions and address computations.
__global__ __launch_bounds__(256)
void boxpool_v13(const float* __restrict__ x, const float* __restrict__ boxes,
                 float* __restrict__ out, int MW, int PM, int jper, unsigned Mj,
                 long featsSize)
{
    __shared__ __align__(16) float roi[CAP_];

    const int Bx   = blockIdx.x;
    const int xcd  = Bx & 7;           // round-robin dispatch -> XCD (perf-only)
    const int s    = Bx >> 3;
    const int nb   = xcd * (NB_ / 8) + (s >> 6);
    const int rem  = s & 63;
    const int c    = rem >> 1;
    const int half = rem & 1;
    const int tid  = threadIdx.x;
    const int n    = nb >> 6;          // B_ = 64

    // ---- box parameters (uniform -> scalar)
    const float* bp = boxes + (long)nb * 4;
    const float xmin = bp[0], ymin = bp[1], xmax = bp[2], ymax = bp[3];
    const bool is_zero = (xmin == 0.f) && (ymin == 0.f) && (xmax == 0.f) && (ymax == 0.f);
    const float bw = xmax - xmin, bh = ymax - ymin;
    const bool wide = bw > bh;
    float den = wide ? bh : bw;
    den = (den == 0.f) ? 1.f : den;
    const float ratio = (wide ? bw : bh) / den;
    const float wf = ceilf(ratio * (float)PH_);
    const float wm1 = (wf > 1.f) ? (wf - 1.f) : 1.f;
    const int   wfi = is_zero ? 0 : (int)wf;

    if (c == 0 && half == 0 && tid == 0) {
        float wv = is_zero ? 0.f : wf;
        out[featsSize + (long)nb * 2 + 0] = wv;
        out[featsSize + (long)nb * 2 + 1] = wv;
    }

    const int jlo  = half * jper;
    const int nv   = min(jper, wfi - jlo);   // # valid j in this half
    const int npts = PH_ * jper;

    float* ob  = out + (long)nb * (2 * C_ * PM) + (long)c * PM;  // d=0 channel base
    float* ob1 = ob + (long)C_ * PM;                             // d=1 channel base

    if (nv <= 0) {
        // whole half invalid (or zero box): zeros at direct positions, both dirs
        for (int p = tid; p < npts; p += 256) {
            const int i  = (int)(((unsigned)p * Mj) >> 16);
            const int jj = p - i * jper;
            const int j  = jlo + jj;
            if (j >= MW) continue;
            ob [(long)i * MW + j] = 0.f;
            ob1[(long)i * MW + j] = 0.f;
        }
        return;
    }

    // ---- geometry
    const float inv7 = 1.f / 7.f;
    const float ew = bw / wm1;      // wide: x step per j
    const float et = bh / wm1;      // tall: y step per j

    float xs_lo, xs_hi, ys_lo, ys_hi;
    if (wide) {
        xs_lo = xmin + (float)jlo * ew;
        xs_hi = xmin + (float)(jlo + nv - 1) * ew;
        ys_lo = ymin;
        ys_hi = ymin + bh;
    } else {
        ys_hi = ymin + (wf - (float)jlo) * et;            // j ascending -> ys descending
        ys_lo = ymin + (wf - (float)(jlo + nv - 1)) * et;
        xs_lo = xmin;
        xs_hi = xmin + bw;
    }
    const int gx0 = min(max((int)floorf(xs_lo - 0.5f), 0), W_ - 1);
    const int gx1 = min(max((int)floorf(xs_hi - 0.5f) + 1, 0), W_ - 1);
    const int gy0 = min(max((int)floorf(ys_lo - 0.5f), 0), H_ - 1);
    const int gy1 = min(max((int)floorf(ys_hi - 0.5f) + 1, 0), H_ - 1);

    // 16B-aligned staging window in x: gxa..gxa+4*CPR-1 covers gx0..gx1.
    // Proof of no row overrun: gxa%4==0, gx1<=255 -> gxa+4*CPR = 4*ceil((gx1+1)/4) <= 256.
    const int gxa  = gx0 & ~3;
    const int CPR  = (gx1 - gxa + 4) >> 2;   // ceil((gx1-gxa+1)/4) data chunks
    const int CPRp = CPR | 1;                // odd chunk count -> bank spread
    const int stride = CPRp << 2;            // LDS row stride in floats
    int rh = gy1 - gy0 + 1;
    if (rh * stride > CAP_) rh = CAP_ / stride;   // defensive (unreachable w/ data)
    const int TC = rh * CPRp;                // total 16B chunks
    const unsigned Mc = (262144u + (unsigned)CPRp - 1u) / (unsigned)CPRp;  // t/CPRp, 2^18

    // ---- stage window -> LDS, 16B chunks (lds dest = per-lane linear = base+lane*16)
    const float* plane = x + (long)(n * C_ + c) * HW_;
    for (int t = tid; t < TC; t += 256) {
        const int row = (int)(((unsigned)t * Mc) >> 18);
        const int ch  = t - row * CPRp;
        const int che = min(ch, CPR - 1);    // pad chunk duplicates last data chunk
        const float* g = plane + (gy0 + row) * W_ + gxa + (che << 2);
        __builtin_amdgcn_global_load_lds(
            (const __attribute__((address_space(1))) unsigned int*)g,
            (__attribute__((address_space(3))) unsigned int*)(&roi[(unsigned)t << 2]),
            16, 0, 0);
    }
    __syncthreads();   // one drain per block; overlap via ~6 resident blocks/CU

    // ---- sample from LDS; write both directions
    for (int p = tid; p < npts; p += 256) {
        const int i  = (int)(((unsigned)p * Mj) >> 16);
        const int jj = p - i * jper;
        const int j  = jlo + jj;
        if (j >= MW) continue;

        float v = 0.f;
        long o1idx;
        if (jj < nv) {
            const float fi = (float)i, fj = (float)j;
            float xs, ys;
            if (wide) { xs = xmin + fj * ew;          ys = ymin + fi * (bh * inv7); }
            else      { xs = xmin + fi * (bw * inv7); ys = ymin + (wf - fj) * et;   }
            const float ix = xs - 0.5f, iy = ys - 0.5f;
            const float x0f = floorf(ix), y0f = floorf(iy);
            const int x0 = (int)x0f, y0 = (int)y0f;

            float wx1 = ix - x0f, wx0 = 1.f - wx1;
            float wy1 = iy - y0f, wy0 = 1.f - wy1;
            if (y0 < 0 || y0 >= H_)         wy0 = 0.f;
            if (y0 + 1 < 0 || y0 + 1 >= H_) wy1 = 0.f;
            const int y0c = min(max(y0, 0), H_ - 1);
            const int y1c = min(max(y0 + 1, 0), H_ - 1);
            if (x0 < 0 || x0 >= W_)         wx0 = 0.f;
            if (x0 + 1 < 0 || x0 + 1 >= W_) wx1 = 0.f;
            const int bx = min(max(x0, 0), W_ - 2);
            const float wl = (bx == x0) ? wx0 : ((bx == x0 + 1) ? wx1 : 0.f);
            const float wr = (bx + 1 == x0 + 1) ? wx1 : ((bx + 1 == x0) ? wx0 : 0.f);

            const int xl  = min(max(bx - gxa, 0), stride - 2);
            const int y0l = min(max(y0c - gy0, 0), rh - 1);
            const int y1l = min(max(y1c - gy0, 0), rh - 1);

            v = (wl * wy0) * roi[y0l * stride + xl] + (wr * wy0) * roi[y0l * stride + xl + 1]
              + (wl * wy1) * roi[y1l * stride + xl] + (wr * wy1) * roi[y1l * stride + xl + 1];

            const int i2 = (PH_ - 1) - i;
            const int j2 = wfi - 1 - j;
            o1idx = (long)i2 * MW + j2;     // valid -> flipped position
        } else {
            o1idx = (long)i * MW + j;       // invalid -> zero at direct position
        }
        ob [(long)i * MW + j] = v;
        ob1[o1idx] = v;
    }
}

extern "C" void kernel_launch(void* const* d_in, const int* in_sizes, int n_in,
                              void* d_out, int out_size, void* d_ws, size_t ws_size,
                              hipStream_t stream)
{
    const float* x     = (const float*)d_in[0];
    const float* boxes = (const float*)d_in[1];
    float* out = (float*)d_out;

    long total      = (long)out_size;
    long widthsSize = (long)N_ * B_ * 2;
    long featsSize  = total - widthsSize;
    int  MW         = (int)(featsSize / ((long)N_ * B_ * 2 * C_ * PH_));
    int  PM         = PH_ * MW;

    int jper = (MW + 1) / 2;                                       // j's per half
    unsigned Mj = (65536u + (unsigned)jper - 1u) / (unsigned)jper; // p/jper magic

    // grid: 8 XCD clusters x 64 boxes x 32 channels x 2 halves
    int blocks = NB_ * C_ * 2;
    hipLaunchKernelGGL(boxpool_v13, dim3(blocks), dim3(256), 0, stream,
                       x, boxes, out, MW, PM, jper, Mj, featsSize);
}